// Round 2
// baseline (230.153 us; speedup 1.0000x reference)
//
#include <hip/hip_runtime.h>
#include <cstdint>
#include <cstddef>

#define GEPS 1e-6f

using bf16x8 = __attribute__((ext_vector_type(8))) short;   // 8 bf16 = 4 VGPRs
using f32x4  = __attribute__((ext_vector_type(4))) float;   // MFMA C/D frag

__device__ inline ushort f2bf(float x) {
    union { float f; uint32_t u; } v; v.f = x;
    uint32_t r = (v.u + 0x7fffu + ((v.u >> 16) & 1u)) >> 16;  // RNE
    return (ushort)r;
}
__device__ inline float bf2f(ushort b) {
    union { float f; uint32_t u; } v; v.u = ((uint32_t)b) << 16;
    return v.f;
}

// async global->LDS, 16 bytes per lane. LDS dest = wave-uniform base + lane*16.
// Global source address IS per-lane (guide §5) -> shifted-conv addressing works.
__device__ inline void gll16(const void* g, void* l) {
    __builtin_amdgcn_global_load_lds(
        (const __attribute__((address_space(1))) void*)g,
        (__attribute__((address_space(3))) void*)l, 16, 0, 0);
}

// ---------------------------------------------------------------------------
// Kernel 1: merged preprocessing (one launch).
//   blocks 0..255     : x -> zero-padded channel-last bf16 Xcl[b][34][34][256]
//   blocks 256..1023  : conv weights -> bf16, k TAP-MAJOR (k = tap*256+ci)
//   blocks 1024..1087 : wo -> bf16 (+ blk 1024 zeroes the fp32 stats accum)
//   blocks 1088..3135 : bias table -> MFMA-fragment-ordered Bx (bf16, DEDICATED)
// ---------------------------------------------------------------------------
__global__ __launch_bounds__(256) void prep_k(
    const float* __restrict__ x,
    const float* __restrict__ wq, const float* __restrict__ wk,
    const float* __restrict__ wv, const float* __restrict__ wo,
    const float* __restrict__ btab,
    ushort* __restrict__ Xcl, ushort* __restrict__ Wbuf,
    ushort* __restrict__ wo_bf, ushort* __restrict__ Bx,
    float* __restrict__ stats)
{
    __shared__ __align__(16) ushort Xs[3 * 34 * 128];   // 25.5 KB (max use)
    int tid = threadIdx.x;
    int blk = blockIdx.x;

    if (blk < 256) {
        // ---- channel-last padded conversion: block = b*32 + y ----
        int b = blk >> 5, y = blk & 31;
#pragma unroll
        for (int it = 0; it < 8; ++it) {
            int idx = it * 256 + tid;           // 0..2047
            int ci = idx >> 3, pxg = idx & 7;
            float4 v = *(const float4*)&x[((size_t)(b * 256 + ci)) * 1024 + y * 32 + pxg * 4];
            int base = (pxg * 4) * 264 + ci;
            Xs[base + 0 * 264] = f2bf(v.x);
            Xs[base + 1 * 264] = f2bf(v.y);
            Xs[base + 2 * 264] = f2bf(v.z);
            Xs[base + 3 * 264] = f2bf(v.w);
        }
        __syncthreads();
        uint4 z4 = make_uint4(0u, 0u, 0u, 0u);
        ushort* orow = Xcl + ((size_t)(b * 34) + y + 1) * 34 * 256;
#pragma unroll
        for (int it = 0; it < 4; ++it) {
            int idx = it * 256 + tid;           // 0..1023
            int px = idx >> 5, ci8 = idx & 31;
            *(uint4*)&orow[(px + 1) * 256 + ci8 * 8] =
                *(const uint4*)&Xs[px * 264 + ci8 * 8];
        }
        if (tid < 64) {                          // x=0 / x=33 border
            int side = tid >> 5, ci8 = tid & 31;
            *(uint4*)&orow[side * 33 * 256 + ci8 * 8] = z4;
        }
        if (y == 0 || y == 31) {                 // y=0 / y=33 border rows
            ushort* zrow = Xcl + ((size_t)(b * 34) + (y == 0 ? 0 : 33)) * 34 * 256;
#pragma unroll
            for (int it = 0; it < 5; ++it) {
                int idx = it * 256 + tid;
                if (idx < 1088) *(uint4*)&zrow[idx * 8] = z4;
            }
        }
        return;
    }
    if (blk < 1024) {
        // ---- conv weight pack (LDS transpose) ----
        int wrow = blk - 256;               // 0..767
        int proj = wrow >> 8, co = wrow & 255;
        const float* src = ((proj == 0) ? wq : ((proj == 1) ? wk : wv)) + (size_t)co * 2304;
#pragma unroll
        for (int j = 0; j < 9; ++j) {
            int idx = j * 256 + tid;
            Xs[idx] = f2bf(src[idx]);       // coalesced fp32 read
        }
        __syncthreads();
        ushort* dst = Wbuf + (size_t)wrow * 2304;
#pragma unroll
        for (int j = 0; j < 9; ++j)          // k = j*256+tid: tap=j, ci=tid
            dst[j * 256 + tid] = Xs[tid * 9 + j];   // coalesced store
        return;
    }
    if (blk < 1088) {
        // ---- wo pack (+ stats zero-init; prep completes before conv GEMM) ----
        if (blk == 1024 && tid < 192) stats[tid] = 0.f;
        int t = (blk - 1024) * 256 + tid;    // 0..16383, 4 elems each
        float4 v = *(const float4*)&wo[(size_t)t * 4];
        union { uint2 u; ushort s[4]; } o;
        o.s[0] = f2bf(v.x); o.s[1] = f2bf(v.y); o.s[2] = f2bf(v.z); o.s[3] = f2bf(v.w);
        *(uint2*)&wo_bf[(size_t)t * 4] = o.u;
        return;
    }
    // ---- Bx expansion ----
    int g = (blk - 1088) * 4 + (tid >> 6);   // tile id 0..8191
    int l = tid & 63;
    int h = g >> 10, qt = (g >> 4) & 63, kt = g & 15;
    int quad = l >> 4, c = l & 15;
    union { uint4 v[2]; ushort s[16]; } o;
#pragma unroll
    for (int f = 0; f < 4; ++f)
#pragma unroll
        for (int r = 0; r < 4; ++r) {
            int qrow = qt * 16 + quad * 4 + r;
            int key = kt * 64 + f * 16 + c;
            int dy = (qrow >> 5) - (key >> 5) + 31;
            int dx = (qrow & 31) - (key & 31) + 31;
            o.s[f * 4 + r] = f2bf(btab[(dy * 63 + dx) * 8 + h]);
        }
    uint4* dst = (uint4*)(Bx + ((size_t)g * 64 + l) * 16);
    dst[0] = o.v[0];
    dst[1] = o.v[1];
}

// ---------------------------------------------------------------------------
// Kernel 2/5: bf16 GEMM  C[M,N] = A[M,K] * B[N,K]^T, 128x64 tile, BK=64,
//   FULL K per block (no split-K).
//   mode 0 (conv as 9 shifted GEMMs): A = Xcl[b][34][34][256], row m=(b,py,px),
//     k=tap*256+ci -> Xcl[b][py+kh][px+kw][ci]. Store bf16 P; fused GroupNorm
//     stats: each block is (proj,b)-pure -> block-reduce fp32 sum/sumsq of its
//     8192 outputs, 2 atomicAdds into stats[96*2] (zeroed by prep_k).
//   mode 1 (out-proj): standard row-major A; store fp32 out[b][o][px] + bias.
// ---------------------------------------------------------------------------
__global__ __launch_bounds__(256, 3) void gemm_bt(
    const ushort* __restrict__ A, const ushort* __restrict__ B,
    int M, int N, int K,
    ushort* __restrict__ Cpart, float* __restrict__ stats,
    float* __restrict__ Cout, const float* __restrict__ bias, int mode)
{
    __shared__ __align__(16) ushort As[128 * 64];
    __shared__ __align__(16) ushort Bs[64 * 64];
    __shared__ float red[8];
    int tid = threadIdx.x;
    int mbase = blockIdx.x * 128, nbase = blockIdx.y * 64;
    int wave = tid >> 6, lane = tid & 63;
    int wm = wave & 1, wn = wave >> 1;          // wave grid 2(M) x 2(N)
    int quad = lane >> 4, c = lane & 15;

    int row_s = tid >> 3;               // 0..31 staging row within chunk
    int cc8 = (tid & 7) ^ (row_s & 7);  // swizzled global column-block
    ushort* ldsA = As + wave * 512;     // wave-uniform dest base (+lane*16B)
    ushort* ldsB = Bs + wave * 512;

    // conv mode: per-thread shifted-GEMM row bases into Xcl (tap-independent)
    int rb[4];
    if (mode == 0) {
#pragma unroll
        for (int R = 0; R < 4; ++R) {
            int r = mbase + R * 32 + row_s;
            int b_ = r >> 10, yy = (r >> 5) & 31, xx = r & 31;
            rb[R] = ((b_ * 34 + yy) * 34 + xx) * 256;
        }
    }

    f32x4 acc[4][2];
#pragma unroll
    for (int i = 0; i < 4; ++i)
#pragma unroll
        for (int j = 0; j < 2; ++j) acc[i][j] = (f32x4){0.f, 0.f, 0.f, 0.f};

    for (int kb = 0; kb < K; kb += 64) {
        __syncthreads();
        if (mode == 0) {
            int tap = kb >> 8;                   // uniform (SALU)
            int kh = (tap * 11) >> 5;            // tap/3 for tap in 0..8
            int kw = tap - kh * 3;
            int toff = (kh * 34 + kw) * 256 + (kb & 255) + cc8 * 8;
#pragma unroll
            for (int R = 0; R < 4; ++R)
                gll16(A + rb[R] + toff, ldsA + R * 2048);
#pragma unroll
            for (int S = 0; S < 2; ++S)
                gll16(B + (size_t)(nbase + S * 32 + row_s) * K + kb + cc8 * 8,
                      ldsB + S * 2048);
        } else {
#pragma unroll
            for (int R = 0; R < 4; ++R)
                gll16(A + (size_t)(mbase + R * 32 + row_s) * K + kb + cc8 * 8,
                      ldsA + R * 2048);
#pragma unroll
            for (int S = 0; S < 2; ++S)
                gll16(B + (size_t)(nbase + S * 32 + row_s) * K + kb + cc8 * 8,
                      ldsB + S * 2048);
        }
        __syncthreads();
#pragma unroll
        for (int kq = 0; kq < 2; ++kq) {
            bf16x8 af[4], bfr[2];
            int sw = ((kq * 4 + quad) ^ (c & 7)) * 8;
#pragma unroll
            for (int i = 0; i < 4; ++i)
                af[i]  = *(const bf16x8*)&As[(wm * 64 + i * 16 + c) * 64 + sw];
#pragma unroll
            for (int j = 0; j < 2; ++j)
                bfr[j] = *(const bf16x8*)&Bs[(wn * 32 + j * 16 + c) * 64 + sw];
#pragma unroll
            for (int i = 0; i < 4; ++i)
#pragma unroll
                for (int j = 0; j < 2; ++j)
                    acc[i][j] = __builtin_amdgcn_mfma_f32_16x16x32_bf16(
                        af[i], bfr[j], acc[i][j], 0, 0, 0);
        }
    }

    if (mode == 0) {
        float s1 = 0.f, s2 = 0.f;
#pragma unroll
        for (int i = 0; i < 4; ++i) {
            int mrow = mbase + wm * 64 + i * 16 + quad * 4;
#pragma unroll
            for (int j = 0; j < 2; ++j) {
                int ncol = nbase + wn * 32 + j * 16 + c;
#pragma unroll
                for (int r = 0; r < 4; ++r) {
                    float v = acc[i][j][r];
                    s1 += v; s2 += v * v;
                    Cpart[(size_t)(mrow + r) * N + ncol] = f2bf(v);
                }
            }
        }
#pragma unroll
        for (int mk = 1; mk < 64; mk <<= 1) {
            s1 += __shfl_xor(s1, mk, 64);
            s2 += __shfl_xor(s2, mk, 64);
        }
        if (lane == 0) { red[wave] = s1; red[4 + wave] = s2; }
        __syncthreads();
        if (tid == 0) {
            int key = (blockIdx.y >> 2) * 8 + (blockIdx.x >> 3);   // proj*8 + b
            atomicAdd(&stats[key * 2 + 0], red[0] + red[1] + red[2] + red[3]);
            atomicAdd(&stats[key * 2 + 1], red[4] + red[5] + red[6] + red[7]);
        }
    } else {
#pragma unroll
        for (int i = 0; i < 4; ++i) {
            int mrow0 = mbase + wm * 64 + i * 16 + quad * 4;
#pragma unroll
            for (int j = 0; j < 2; ++j) {
                int ncol = nbase + wn * 32 + j * 16 + c;
                int bb = ncol >> 10, px = ncol & 1023;
#pragma unroll
                for (int r = 0; r < 4; ++r) {
                    int o = mrow0 + r;
                    Cout[((size_t)bb * 256 + o) * 1024 + px] = acc[i][j][r] + bias[o];
                }
            }
        }
    }
}

// ---------------------------------------------------------------------------
// Kernel 3: GroupNorm(1) + exact GELU + head reshape from single bf16 P.
//   q/k -> [b][h][n][d]; V -> fragment order Vx.
// ---------------------------------------------------------------------------
__global__ void gn_k(const ushort* __restrict__ P0,
                     const float* __restrict__ stats,
                     const float* __restrict__ gq, const float* __restrict__ bq,
                     const float* __restrict__ gk, const float* __restrict__ bk,
                     const float* __restrict__ gv, const float* __restrict__ bv,
                     ushort* __restrict__ qb, ushort* __restrict__ kb2,
                     ushort* __restrict__ vx)
{
    int t = blockIdx.x * 256 + threadIdx.x;     // 786432 threads x 8 elems
    int m = t / 96;
    int nn = (t - m * 96) * 8;
    int proj = nn >> 8, co = nn & 255;
    int b = m >> 10, px = m & 1023;
    float s1 = stats[(proj * 8 + b) * 2 + 0];
    float s2 = stats[(proj * 8 + b) * 2 + 1];
    const float Ninv = 1.f / 262144.f;
    float mu = s1 * Ninv;
    float var = fmaxf(s2 * Ninv - mu * mu, 0.f);
    float rsig = rsqrtf(var + GEPS);
    const float* gam = (proj == 0) ? gq : ((proj == 1) ? gk : gv);
    const float* bet = (proj == 0) ? bq : ((proj == 1) ? bk : bv);

    size_t base = (size_t)m * 768 + nn;
    union { uint4 v; ushort s[8]; } a;
    a.v = *(const uint4*)&P0[base];
    union { uint4 v; ushort s[8]; } outp;
#pragma unroll
    for (int e = 0; e < 8; ++e) {
        int cc = co + e;
        float xv = bf2f(a.s[e]);
        float xn = (xv - mu) * rsig * gam[cc] + bet[cc];
        float ge = 0.5f * xn * (1.f + erff(xn * 0.70710678118654752f));
        outp.s[e] = f2bf(ge);
    }
    int h = co >> 5, d = co & 31;
    if (proj == 0) {
        *(uint4*)(qb + ((((size_t)b * 8 + h) * 1024 + px) * 32 + d)) = outp.v;
    } else if (proj == 1) {
        *(uint4*)(kb2 + ((((size_t)b * 8 + h) * 1024 + px) * 32 + d)) = outp.v;
    } else {
        // Vx[bh][kca=px>>5][half=d>>4][lane=quad*16+(d&15)][j=px&7]
        ushort* vb = vx + ((size_t)b * 8 + h) * 32768;
        int kca = px >> 5, quad = (px >> 3) & 3, j = px & 7;
#pragma unroll
        for (int e = 0; e < 8; ++e) {
            int dd = d + e;
            vb[(((kca * 2 + (dd >> 4)) * 64) + quad * 16 + (dd & 15)) * 8 + j] = outp.s[e];
        }
    }
}

// ---------------------------------------------------------------------------
// Kernel 4: fused attention, FULL key range per block (1024 blocks, 4/CU).
//   Normalizes in-kernel and writes attnout [b][n][h*32+d] directly.
// ---------------------------------------------------------------------------
__global__ __launch_bounds__(256, 8) void attn_k(
    const ushort* __restrict__ qb, const ushort* __restrict__ kb,
    const ushort* __restrict__ vx, const ushort* __restrict__ Bx,
    ushort* __restrict__ attnout)
{
    __shared__ __align__(16) ushort Pl[4 * 16 * 72];
    int tid = threadIdx.x, wave = tid >> 6, lane = tid & 63;
    int quad = lane >> 4, c = lane & 15;
    int bh = blockIdx.y;               // b*8 + h
    int h = bh & 7;
    int qbase = blockIdx.x * 64 + wave * 16;

    const ushort* Q  = qb + (size_t)bh * 1024 * 32;
    const ushort* Kp = kb + (size_t)bh * 1024 * 32;
    const ushort* Vb = vx + (size_t)bh * 32768;
    const ushort* bxp = Bx + (((size_t)(h * 64 + (qbase >> 4)) * 16) * 64 + lane) * 16;
    ushort* Pw = Pl + wave * 16 * 72;

    bf16x8 qf = *(const bf16x8*)&Q[(qbase + c) * 32 + quad * 8];

    float l_[4] = {0.f, 0.f, 0.f, 0.f};
    f32x4 Of0 = {0.f, 0.f, 0.f, 0.f}, Of1 = {0.f, 0.f, 0.f, 0.f};

    for (int kb64 = 0; kb64 < 1024; kb64 += 64) {
        f32x4 S[4];
        f32x4 zf = {0.f, 0.f, 0.f, 0.f};
#pragma unroll
        for (int f = 0; f < 4; ++f) {
            bf16x8 kf = *(const bf16x8*)&Kp[(kb64 + f * 16 + c) * 32 + quad * 8];
            S[f] = __builtin_amdgcn_mfma_f32_16x16x32_bf16(qf, kf, zf, 0, 0, 0);
        }
        // fragment-ordered bias: 32 B per lane, coalesced
        union { uint4 v[2]; ushort s[16]; } bu;
        const uint4* bsrc = (const uint4*)(bxp + (size_t)(kb64 >> 6) * 1024);
        bu.v[0] = bsrc[0];
        bu.v[1] = bsrc[1];
#pragma unroll
        for (int f = 0; f < 4; ++f)
#pragma unroll
            for (int r = 0; r < 4; ++r) {
                float p = __expf(S[f][r] + bf2f(bu.s[f * 4 + r]));
                S[f][r] = p;
                l_[r] += p;
            }
        // P (C-layout) -> LDS -> A-layout; per-wave slice, no barrier needed
#pragma unroll
        for (int f = 0; f < 4; ++f)
#pragma unroll
            for (int r = 0; r < 4; ++r)
                Pw[(quad * 4 + r) * 72 + f * 16 + c] = f2bf(S[f][r]);
#pragma unroll
        for (int kc = 0; kc < 2; ++kc) {
            int kca = (kb64 >> 5) + kc;
            bf16x8 pf = *(const bf16x8*)&Pw[c * 72 + kc * 32 + quad * 8];
            bf16x8 vf0 = *(const bf16x8*)&Vb[((kca * 2 + 0) * 64 + lane) * 8];
            Of0 = __builtin_amdgcn_mfma_f32_16x16x32_bf16(pf, vf0, Of0, 0, 0, 0);
            bf16x8 vf1 = *(const bf16x8*)&Vb[((kca * 2 + 1) * 64 + lane) * 8];
            Of1 = __builtin_amdgcn_mfma_f32_16x16x32_bf16(pf, vf1, Of1, 0, 0, 0);
        }
    }
    int b = bh >> 3;
#pragma unroll
    for (int r = 0; r < 4; ++r) {
        float l = l_[r];
        l += __shfl_xor(l, 1, 64);
        l += __shfl_xor(l, 2, 64);
        l += __shfl_xor(l, 4, 64);
        l += __shfl_xor(l, 8, 64);
        float inv = 1.f / l;
        int qr = qbase + quad * 4 + r;
        ushort* dst = attnout + ((size_t)b * 1024 + qr) * 256 + h * 32;
        dst[c]      = f2bf(Of0[r] * inv);
        dst[16 + c] = f2bf(Of1[r] * inv);
    }
}

// ---------------------------------------------------------------------------
extern "C" void kernel_launch(void* const* d_in, const int* in_sizes, int n_in,
                              void* d_out, int out_size, void* d_ws, size_t ws_size,
                              hipStream_t stream)
{
    const float* x    = (const float*)d_in[0];
    const float* wq   = (const float*)d_in[1];
    const float* wk   = (const float*)d_in[2];
    const float* wv   = (const float*)d_in[3];
    const float* gq   = (const float*)d_in[4];
    const float* bq   = (const float*)d_in[5];
    const float* gk   = (const float*)d_in[6];
    const float* bk   = (const float*)d_in[7];
    const float* gv   = (const float*)d_in[8];
    const float* bv   = (const float*)d_in[9];
    const float* btab = (const float*)d_in[10];
    const float* wo   = (const float*)d_in[11];
    const float* bo   = (const float*)d_in[12];
    float* out = (float*)d_out;

    char* w = (char*)d_ws;
    size_t off = 0;
    auto alloc = [&](size_t bytes) -> char* {
        char* p = w + off;
        off += (bytes + 255) & ~(size_t)255;
        return p;
    };
    ushort* Xcl     = (ushort*)alloc(8ull * 34 * 34 * 256 * 2); // padded chan-last x (4.7 MB)
    ushort* Wbuf    = (ushort*)alloc(768ull * 2304 * 2);    // concat conv weights
    ushort* wo_bf   = (ushort*)alloc(65536ull * 2);         // out-proj weight
    ushort* Bx      = (ushort*)alloc(8192ull * 64 * 16 * 2);// bias frags (16.7 MB, DEDICATED)
    ushort* P0      = (ushort*)alloc(8192ull * 768 * 2);    // conv output bf16 (12.6 MB)
    float*  stats   = (float*)alloc(768);                   // [proj][b][sum,sumsq] fp32 accum
    ushort* qb      = (ushort*)alloc(8ull * 8 * 1024 * 32 * 2);   // 4 MB
    ushort* kb2     = (ushort*)alloc(8ull * 8 * 1024 * 32 * 2);   // 4 MB
    ushort* vx      = (ushort*)alloc(8ull * 8 * 32 * 1024 * 2);   // 4 MB (fragment order)
    ushort* attnout = (ushort*)alloc(8ull * 1024 * 256 * 2);      // 4 MB

    prep_k<<<3136, 256, 0, stream>>>(x, wq, wk, wv, wo, btab,
                                     Xcl, Wbuf, wo_bf, Bx, stats);
    gemm_bt<<<dim3(64, 12, 1), 256, 0, stream>>>(Xcl, Wbuf, 8192, 768, 2304,
                                                 P0, stats, nullptr, nullptr, 0);
    gn_k<<<3072, 256, 0, stream>>>(P0, stats, gq, bq, gk, bk, gv, bv,
                                   qb, kb2, vx);
    attn_k<<<dim3(16, 64, 1), 256, 0, stream>>>(qb, kb2, vx, Bx, attnout);
    gemm_bt<<<dim3(2, 128, 1), 256, 0, stream>>>(wo_bf, attnout, 256, 8192, 256,
                                                 nullptr, nullptr, out, bo, 1);
}

// Round 3
// 221.230 us; speedup vs baseline: 1.0403x; 1.0403x over previous
//
#include <hip/hip_runtime.h>
#include <cstdint>
#include <cstddef>

#define GEPS 1e-6f

using bf16x8 = __attribute__((ext_vector_type(8))) short;   // 8 bf16 = 4 VGPRs
using f32x4  = __attribute__((ext_vector_type(4))) float;   // MFMA C/D frag

__device__ inline ushort f2bf(float x) {
    union { float f; uint32_t u; } v; v.f = x;
    uint32_t r = (v.u + 0x7fffu + ((v.u >> 16) & 1u)) >> 16;  // RNE
    return (ushort)r;
}
__device__ inline float bf2f(ushort b) {
    union { float f; uint32_t u; } v; v.u = ((uint32_t)b) << 16;
    return v.f;
}

// async global->LDS, 16 bytes per lane. LDS dest = wave-uniform base + lane*16.
// Global source address IS per-lane (guide §5) -> shifted-conv addressing works.
__device__ inline void gll16(const void* g, void* l) {
    __builtin_amdgcn_global_load_lds(
        (const __attribute__((address_space(1))) void*)g,
        (__attribute__((address_space(3))) void*)l, 16, 0, 0);
}

// ---------------------------------------------------------------------------
// Kernel 1: merged preprocessing (one launch).
//   blocks 0..255     : x -> zero-padded channel-last bf16 Xcl[b][34][34][256]
//   blocks 256..1023  : conv weights -> bf16, k TAP-MAJOR (k = tap*256+ci)
//   blocks 1024..1087 : wo -> bf16 (+ blk 1024 zeroes the fp32 stats accum)
//   blocks 1088..3135 : bias table -> MFMA-fragment-ordered Bx (bf16, DEDICATED)
// ---------------------------------------------------------------------------
__global__ __launch_bounds__(256) void prep_k(
    const float* __restrict__ x,
    const float* __restrict__ wq, const float* __restrict__ wk,
    const float* __restrict__ wv, const float* __restrict__ wo,
    const float* __restrict__ btab,
    ushort* __restrict__ Xcl, ushort* __restrict__ Wbuf,
    ushort* __restrict__ wo_bf, ushort* __restrict__ Bx,
    float* __restrict__ stats)
{
    __shared__ __align__(16) ushort Xs[3 * 34 * 128];   // 25.5 KB (max use)
    int tid = threadIdx.x;
    int blk = blockIdx.x;

    if (blk < 256) {
        // ---- channel-last padded conversion: block = b*32 + y ----
        int b = blk >> 5, y = blk & 31;
#pragma unroll
        for (int it = 0; it < 8; ++it) {
            int idx = it * 256 + tid;           // 0..2047
            int ci = idx >> 3, pxg = idx & 7;
            float4 v = *(const float4*)&x[((size_t)(b * 256 + ci)) * 1024 + y * 32 + pxg * 4];
            int base = (pxg * 4) * 264 + ci;
            Xs[base + 0 * 264] = f2bf(v.x);
            Xs[base + 1 * 264] = f2bf(v.y);
            Xs[base + 2 * 264] = f2bf(v.z);
            Xs[base + 3 * 264] = f2bf(v.w);
        }
        __syncthreads();
        uint4 z4 = make_uint4(0u, 0u, 0u, 0u);
        ushort* orow = Xcl + ((size_t)(b * 34) + y + 1) * 34 * 256;
#pragma unroll
        for (int it = 0; it < 4; ++it) {
            int idx = it * 256 + tid;           // 0..1023
            int px = idx >> 5, ci8 = idx & 31;
            *(uint4*)&orow[(px + 1) * 256 + ci8 * 8] =
                *(const uint4*)&Xs[px * 264 + ci8 * 8];
        }
        if (tid < 64) {                          // x=0 / x=33 border
            int side = tid >> 5, ci8 = tid & 31;
            *(uint4*)&orow[side * 33 * 256 + ci8 * 8] = z4;
        }
        if (y == 0 || y == 31) {                 // y=0 / y=33 border rows
            ushort* zrow = Xcl + ((size_t)(b * 34) + (y == 0 ? 0 : 33)) * 34 * 256;
#pragma unroll
            for (int it = 0; it < 5; ++it) {
                int idx = it * 256 + tid;
                if (idx < 1088) *(uint4*)&zrow[idx * 8] = z4;
            }
        }
        return;
    }
    if (blk < 1024) {
        // ---- conv weight pack (LDS transpose) ----
        int wrow = blk - 256;               // 0..767
        int proj = wrow >> 8, co = wrow & 255;
        const float* src = ((proj == 0) ? wq : ((proj == 1) ? wk : wv)) + (size_t)co * 2304;
#pragma unroll
        for (int j = 0; j < 9; ++j) {
            int idx = j * 256 + tid;
            Xs[idx] = f2bf(src[idx]);       // coalesced fp32 read
        }
        __syncthreads();
        ushort* dst = Wbuf + (size_t)wrow * 2304;
#pragma unroll
        for (int j = 0; j < 9; ++j)          // k = j*256+tid: tap=j, ci=tid
            dst[j * 256 + tid] = Xs[tid * 9 + j];   // coalesced store
        return;
    }
    if (blk < 1088) {
        // ---- wo pack (+ stats zero-init; prep completes before conv GEMM) ----
        if (blk == 1024 && tid < 192) stats[tid] = 0.f;
        int t = (blk - 1024) * 256 + tid;    // 0..16383, 4 elems each
        float4 v = *(const float4*)&wo[(size_t)t * 4];
        union { uint2 u; ushort s[4]; } o;
        o.s[0] = f2bf(v.x); o.s[1] = f2bf(v.y); o.s[2] = f2bf(v.z); o.s[3] = f2bf(v.w);
        *(uint2*)&wo_bf[(size_t)t * 4] = o.u;
        return;
    }
    // ---- Bx expansion ----
    int g = (blk - 1088) * 4 + (tid >> 6);   // tile id 0..8191
    int l = tid & 63;
    int h = g >> 10, qt = (g >> 4) & 63, kt = g & 15;
    int quad = l >> 4, c = l & 15;
    union { uint4 v[2]; ushort s[16]; } o;
#pragma unroll
    for (int f = 0; f < 4; ++f)
#pragma unroll
        for (int r = 0; r < 4; ++r) {
            int qrow = qt * 16 + quad * 4 + r;
            int key = kt * 64 + f * 16 + c;
            int dy = (qrow >> 5) - (key >> 5) + 31;
            int dx = (qrow & 31) - (key & 31) + 31;
            o.s[f * 4 + r] = f2bf(btab[(dy * 63 + dx) * 8 + h]);
        }
    uint4* dst = (uint4*)(Bx + ((size_t)g * 64 + l) * 16);
    dst[0] = o.v[0];
    dst[1] = o.v[1];
}

// ---------------------------------------------------------------------------
// Kernel 2/5: bf16 GEMM  C[M,N] = A[M,K] * B[N,K]^T, 128x64 tile, BK=64,
//   FULL K per block (no split-K).
//   mode 0 (conv as 9 shifted GEMMs): A = Xcl[b][34][34][256], row m=(b,py,px),
//     k=tap*256+ci -> Xcl[b][py+kh][px+kw][ci]. Store bf16 P; fused GroupNorm
//     stats: each block is (proj,b)-pure -> block-reduce fp32 sum/sumsq of its
//     8192 outputs, 2 atomicAdds into stats[96*2] (zeroed by prep_k).
//   mode 1 (out-proj): standard row-major A; store fp32 out[b][o][px] + bias.
// ---------------------------------------------------------------------------
__global__ __launch_bounds__(256, 3) void gemm_bt(
    const ushort* __restrict__ A, const ushort* __restrict__ B,
    int M, int N, int K,
    ushort* __restrict__ Cpart, float* __restrict__ stats,
    float* __restrict__ Cout, const float* __restrict__ bias, int mode)
{
    __shared__ __align__(16) ushort As[128 * 64];
    __shared__ __align__(16) ushort Bs[64 * 64];
    __shared__ float red[8];
    int tid = threadIdx.x;
    int mbase = blockIdx.x * 128, nbase = blockIdx.y * 64;
    int wave = tid >> 6, lane = tid & 63;
    int wm = wave & 1, wn = wave >> 1;          // wave grid 2(M) x 2(N)
    int quad = lane >> 4, c = lane & 15;

    int row_s = tid >> 3;               // 0..31 staging row within chunk
    int cc8 = (tid & 7) ^ (row_s & 7);  // swizzled global column-block
    ushort* ldsA = As + wave * 512;     // wave-uniform dest base (+lane*16B)
    ushort* ldsB = Bs + wave * 512;

    // conv mode: per-thread shifted-GEMM row bases into Xcl (tap-independent)
    int rb[4];
    if (mode == 0) {
#pragma unroll
        for (int R = 0; R < 4; ++R) {
            int r = mbase + R * 32 + row_s;
            int b_ = r >> 10, yy = (r >> 5) & 31, xx = r & 31;
            rb[R] = ((b_ * 34 + yy) * 34 + xx) * 256;
        }
    }

    f32x4 acc[4][2];
#pragma unroll
    for (int i = 0; i < 4; ++i)
#pragma unroll
        for (int j = 0; j < 2; ++j) acc[i][j] = (f32x4){0.f, 0.f, 0.f, 0.f};

    for (int kb = 0; kb < K; kb += 64) {
        __syncthreads();
        if (mode == 0) {
            int tap = kb >> 8;                   // uniform (SALU)
            int kh = (tap * 11) >> 5;            // tap/3 for tap in 0..8
            int kw = tap - kh * 3;
            int toff = (kh * 34 + kw) * 256 + (kb & 255) + cc8 * 8;
#pragma unroll
            for (int R = 0; R < 4; ++R)
                gll16(A + rb[R] + toff, ldsA + R * 2048);
#pragma unroll
            for (int S = 0; S < 2; ++S)
                gll16(B + (size_t)(nbase + S * 32 + row_s) * K + kb + cc8 * 8,
                      ldsB + S * 2048);
        } else {
#pragma unroll
            for (int R = 0; R < 4; ++R)
                gll16(A + (size_t)(mbase + R * 32 + row_s) * K + kb + cc8 * 8,
                      ldsA + R * 2048);
#pragma unroll
            for (int S = 0; S < 2; ++S)
                gll16(B + (size_t)(nbase + S * 32 + row_s) * K + kb + cc8 * 8,
                      ldsB + S * 2048);
        }
        __syncthreads();
#pragma unroll
        for (int kq = 0; kq < 2; ++kq) {
            bf16x8 af[4], bfr[2];
            int sw = ((kq * 4 + quad) ^ (c & 7)) * 8;
#pragma unroll
            for (int i = 0; i < 4; ++i)
                af[i]  = *(const bf16x8*)&As[(wm * 64 + i * 16 + c) * 64 + sw];
#pragma unroll
            for (int j = 0; j < 2; ++j)
                bfr[j] = *(const bf16x8*)&Bs[(wn * 32 + j * 16 + c) * 64 + sw];
#pragma unroll
            for (int i = 0; i < 4; ++i)
#pragma unroll
                for (int j = 0; j < 2; ++j)
                    acc[i][j] = __builtin_amdgcn_mfma_f32_16x16x32_bf16(
                        af[i], bfr[j], acc[i][j], 0, 0, 0);
        }
    }

    if (mode == 0) {
        float s1 = 0.f, s2 = 0.f;
#pragma unroll
        for (int i = 0; i < 4; ++i) {
            int mrow = mbase + wm * 64 + i * 16 + quad * 4;
#pragma unroll
            for (int j = 0; j < 2; ++j) {
                int ncol = nbase + wn * 32 + j * 16 + c;
#pragma unroll
                for (int r = 0; r < 4; ++r) {
                    float v = acc[i][j][r];
                    s1 += v; s2 += v * v;
                    Cpart[(size_t)(mrow + r) * N + ncol] = f2bf(v);
                }
            }
        }
#pragma unroll
        for (int mk = 1; mk < 64; mk <<= 1) {
            s1 += __shfl_xor(s1, mk, 64);
            s2 += __shfl_xor(s2, mk, 64);
        }
        if (lane == 0) { red[wave] = s1; red[4 + wave] = s2; }
        __syncthreads();
        if (tid == 0) {
            int key = (blockIdx.y >> 2) * 8 + (blockIdx.x >> 3);   // proj*8 + b
            atomicAdd(&stats[key * 2 + 0], red[0] + red[1] + red[2] + red[3]);
            atomicAdd(&stats[key * 2 + 1], red[4] + red[5] + red[6] + red[7]);
        }
    } else {
#pragma unroll
        for (int i = 0; i < 4; ++i) {
            int mrow0 = mbase + wm * 64 + i * 16 + quad * 4;
#pragma unroll
            for (int j = 0; j < 2; ++j) {
                int ncol = nbase + wn * 32 + j * 16 + c;
                int bb = ncol >> 10, px = ncol & 1023;
#pragma unroll
                for (int r = 0; r < 4; ++r) {
                    int o = mrow0 + r;
                    Cout[((size_t)bb * 256 + o) * 1024 + px] = acc[i][j][r] + bias[o];
                }
            }
        }
    }
}

// ---------------------------------------------------------------------------
// Kernel 3: GroupNorm(1) + exact GELU + head reshape from single bf16 P.
//   q/k -> [b][h][n][d]; V -> fragment order Vx.
// ---------------------------------------------------------------------------
__global__ void gn_k(const ushort* __restrict__ P0,
                     const float* __restrict__ stats,
                     const float* __restrict__ gq, const float* __restrict__ bq,
                     const float* __restrict__ gk, const float* __restrict__ bk,
                     const float* __restrict__ gv, const float* __restrict__ bv,
                     ushort* __restrict__ qb, ushort* __restrict__ kb2,
                     ushort* __restrict__ vx)
{
    int t = blockIdx.x * 256 + threadIdx.x;     // 786432 threads x 8 elems
    int m = t / 96;
    int nn = (t - m * 96) * 8;
    int proj = nn >> 8, co = nn & 255;
    int b = m >> 10, px = m & 1023;
    float s1 = stats[(proj * 8 + b) * 2 + 0];
    float s2 = stats[(proj * 8 + b) * 2 + 1];
    const float Ninv = 1.f / 262144.f;
    float mu = s1 * Ninv;
    float var = fmaxf(s2 * Ninv - mu * mu, 0.f);
    float rsig = rsqrtf(var + GEPS);
    const float* gam = (proj == 0) ? gq : ((proj == 1) ? gk : gv);
    const float* bet = (proj == 0) ? bq : ((proj == 1) ? bk : bv);

    size_t base = (size_t)m * 768 + nn;
    union { uint4 v; ushort s[8]; } a;
    a.v = *(const uint4*)&P0[base];
    union { uint4 v; ushort s[8]; } outp;
#pragma unroll
    for (int e = 0; e < 8; ++e) {
        int cc = co + e;
        float xv = bf2f(a.s[e]);
        float xn = (xv - mu) * rsig * gam[cc] + bet[cc];
        float ge = 0.5f * xn * (1.f + erff(xn * 0.70710678118654752f));
        outp.s[e] = f2bf(ge);
    }
    int h = co >> 5, d = co & 31;
    if (proj == 0) {
        *(uint4*)(qb + ((((size_t)b * 8 + h) * 1024 + px) * 32 + d)) = outp.v;
    } else if (proj == 1) {
        *(uint4*)(kb2 + ((((size_t)b * 8 + h) * 1024 + px) * 32 + d)) = outp.v;
    } else {
        // Vx[bh][kca=px>>5][half=d>>4][lane=quad*16+(d&15)][j=px&7]
        ushort* vb = vx + ((size_t)b * 8 + h) * 32768;
        int kca = px >> 5, quad = (px >> 3) & 3, j = px & 7;
#pragma unroll
        for (int e = 0; e < 8; ++e) {
            int dd = d + e;
            vb[(((kca * 2 + (dd >> 4)) * 64) + quad * 16 + (dd & 15)) * 8 + j] = outp.s[e];
        }
    }
}

// ---------------------------------------------------------------------------
// Kernel 4: fused attention, KEY-SPLIT z=2 (2048 blocks -> 8 blocks/CU, 100%
//   occupancy ceiling — latency-bound kernel needs the TLP; z=1 measured 38%
//   occupancy / 49 µs vs ~27 µs here). Writes UNNORMALIZED bf16 O partials +
//   fp32 l partials; combine_k finishes.
// ---------------------------------------------------------------------------
__global__ __launch_bounds__(256, 8) void attn_k(
    const ushort* __restrict__ qb, const ushort* __restrict__ kb,
    const ushort* __restrict__ vx, const ushort* __restrict__ Bx,
    ushort* __restrict__ Opart, float* __restrict__ lpart)
{
    __shared__ __align__(16) ushort Pl[4 * 16 * 72];
    int tid = threadIdx.x, wave = tid >> 6, lane = tid & 63;
    int quad = lane >> 4, c = lane & 15;
    int bh = blockIdx.y;               // b*8 + h
    int h = bh & 7;
    int z = blockIdx.z;
    int qbase = blockIdx.x * 64 + wave * 16;

    const ushort* Q  = qb + (size_t)bh * 1024 * 32;
    const ushort* Kp = kb + (size_t)bh * 1024 * 32;
    const ushort* Vb = vx + (size_t)bh * 32768;
    const ushort* bxp = Bx + (((size_t)(h * 64 + (qbase >> 4)) * 16) * 64 + lane) * 16;
    ushort* Pw = Pl + wave * 16 * 72;

    bf16x8 qf = *(const bf16x8*)&Q[(qbase + c) * 32 + quad * 8];

    float l_[4] = {0.f, 0.f, 0.f, 0.f};
    f32x4 Of0 = {0.f, 0.f, 0.f, 0.f}, Of1 = {0.f, 0.f, 0.f, 0.f};

    for (int kb64 = z * 512; kb64 < z * 512 + 512; kb64 += 64) {
        f32x4 S[4];
        f32x4 zf = {0.f, 0.f, 0.f, 0.f};
#pragma unroll
        for (int f = 0; f < 4; ++f) {
            bf16x8 kf = *(const bf16x8*)&Kp[(kb64 + f * 16 + c) * 32 + quad * 8];
            S[f] = __builtin_amdgcn_mfma_f32_16x16x32_bf16(qf, kf, zf, 0, 0, 0);
        }
        // fragment-ordered bias: 32 B per lane, coalesced
        union { uint4 v[2]; ushort s[16]; } bu;
        const uint4* bsrc = (const uint4*)(bxp + (size_t)(kb64 >> 6) * 1024);
        bu.v[0] = bsrc[0];
        bu.v[1] = bsrc[1];
#pragma unroll
        for (int f = 0; f < 4; ++f)
#pragma unroll
            for (int r = 0; r < 4; ++r) {
                float p = __expf(S[f][r] + bf2f(bu.s[f * 4 + r]));
                S[f][r] = p;
                l_[r] += p;
            }
        // P (C-layout) -> LDS -> A-layout; per-wave slice, no barrier needed
#pragma unroll
        for (int f = 0; f < 4; ++f)
#pragma unroll
            for (int r = 0; r < 4; ++r)
                Pw[(quad * 4 + r) * 72 + f * 16 + c] = f2bf(S[f][r]);
#pragma unroll
        for (int kc = 0; kc < 2; ++kc) {
            int kca = (kb64 >> 5) + kc;
            bf16x8 pf = *(const bf16x8*)&Pw[c * 72 + kc * 32 + quad * 8];
            bf16x8 vf0 = *(const bf16x8*)&Vb[((kca * 2 + 0) * 64 + lane) * 8];
            Of0 = __builtin_amdgcn_mfma_f32_16x16x32_bf16(pf, vf0, Of0, 0, 0, 0);
            bf16x8 vf1 = *(const bf16x8*)&Vb[((kca * 2 + 1) * 64 + lane) * 8];
            Of1 = __builtin_amdgcn_mfma_f32_16x16x32_bf16(pf, vf1, Of1, 0, 0, 0);
        }
    }
#pragma unroll
    for (int r = 0; r < 4; ++r) {
        float l = l_[r];
        l += __shfl_xor(l, 1, 64);
        l += __shfl_xor(l, 2, 64);
        l += __shfl_xor(l, 4, 64);
        l += __shfl_xor(l, 8, 64);
        int qr = qbase + quad * 4 + r;
        size_t ob = (((size_t)z * 64 + bh) * 1024 + qr) * 32;
        Opart[ob + c]      = f2bf(Of0[r]);
        Opart[ob + 16 + c] = f2bf(Of1[r]);
        if (c == 0) lpart[(size_t)z * 65536 + bh * 1024 + qr] = l;
    }
}

// ---------------------------------------------------------------------------
// Kernel 5: combine key-split partials: attnout = (O0+O1)/(l0+l1), bf16,
//   written in [b][n][h*32+d] layout for the out-proj GEMM.
// ---------------------------------------------------------------------------
__global__ __launch_bounds__(256) void combine_k(const ushort* __restrict__ Opart,
                                                 const float* __restrict__ lpart,
                                                 ushort* __restrict__ attnout)
{
    int t = blockIdx.x * 256 + threadIdx.x;   // 262144 threads, 8 d each
    int g = t & 3;
    int qg = t >> 2;                          // bh*1024 + qr
    int bh = qg >> 10, qr = qg & 1023;
    int b = bh >> 3, h = bh & 7;
    size_t ob = ((size_t)qg) * 32 + g * 8;
    union { uint4 v; ushort s[8]; } o0, o1;
    o0.v = *(const uint4*)&Opart[ob];
    o1.v = *(const uint4*)&Opart[(size_t)64 * 1024 * 32 + ob];
    float inv = 1.f / (lpart[qg] + lpart[65536 + qg]);
    union { uint4 u; ushort s[8]; } o;
#pragma unroll
    for (int e = 0; e < 8; ++e)
        o.s[e] = f2bf((bf2f(o0.s[e]) + bf2f(o1.s[e])) * inv);
    *(uint4*)&attnout[(((size_t)b * 1024 + qr) * 256) + h * 32 + g * 8] = o.u;
}

// ---------------------------------------------------------------------------
extern "C" void kernel_launch(void* const* d_in, const int* in_sizes, int n_in,
                              void* d_out, int out_size, void* d_ws, size_t ws_size,
                              hipStream_t stream)
{
    const float* x    = (const float*)d_in[0];
    const float* wq   = (const float*)d_in[1];
    const float* wk   = (const float*)d_in[2];
    const float* wv   = (const float*)d_in[3];
    const float* gq   = (const float*)d_in[4];
    const float* bq   = (const float*)d_in[5];
    const float* gk   = (const float*)d_in[6];
    const float* bk   = (const float*)d_in[7];
    const float* gv   = (const float*)d_in[8];
    const float* bv   = (const float*)d_in[9];
    const float* btab = (const float*)d_in[10];
    const float* wo   = (const float*)d_in[11];
    const float* bo   = (const float*)d_in[12];
    float* out = (float*)d_out;

    char* w = (char*)d_ws;
    size_t off = 0;
    auto alloc = [&](size_t bytes) -> char* {
        char* p = w + off;
        off += (bytes + 255) & ~(size_t)255;
        return p;
    };
    ushort* Xcl     = (ushort*)alloc(8ull * 34 * 34 * 256 * 2); // padded chan-last x (4.7 MB)
    ushort* Wbuf    = (ushort*)alloc(768ull * 2304 * 2);    // concat conv weights
    ushort* wo_bf   = (ushort*)alloc(65536ull * 2);         // out-proj weight
    ushort* Bx      = (ushort*)alloc(8192ull * 64 * 16 * 2);// bias frags (16.7 MB, DEDICATED)
    ushort* P0      = (ushort*)alloc(8192ull * 768 * 2);    // conv output bf16 (12.6 MB)
    float*  stats   = (float*)alloc(768);                   // [proj][b][sum,sumsq] fp32 accum
    ushort* Opart   = (ushort*)alloc(2ull * 64 * 1024 * 32 * 2);  // attn O partials (bf16)
    float*  lpart   = (float*)alloc(2ull * 64 * 1024 * 4);        // attn l partials
    ushort* qb      = (ushort*)alloc(8ull * 8 * 1024 * 32 * 2);   // 4 MB
    ushort* kb2     = (ushort*)alloc(8ull * 8 * 1024 * 32 * 2);   // 4 MB
    ushort* vx      = (ushort*)alloc(8ull * 8 * 32 * 1024 * 2);   // 4 MB (fragment order)
    ushort* attnout = (ushort*)alloc(8ull * 1024 * 256 * 2);      // 4 MB

    prep_k<<<3136, 256, 0, stream>>>(x, wq, wk, wv, wo, btab,
                                     Xcl, Wbuf, wo_bf, Bx, stats);
    gemm_bt<<<dim3(64, 12, 1), 256, 0, stream>>>(Xcl, Wbuf, 8192, 768, 2304,
                                                 P0, stats, nullptr, nullptr, 0);
    gn_k<<<3072, 256, 0, stream>>>(P0, stats, gq, bq, gk, bk, gv, bv,
                                   qb, kb2, vx);
    attn_k<<<dim3(16, 64, 2), 256, 0, stream>>>(qb, kb2, vx, Bx, Opart, lpart);
    combine_k<<<1024, 256, 0, stream>>>(Opart, lpart, attnout);
    gemm_bt<<<dim3(2, 128, 1), 256, 0, stream>>>(wo_bf, attnout, 256, 8192, 256,
                                                 nullptr, nullptr, out, bo, 1);
}

// Round 4
// 220.273 us; speedup vs baseline: 1.0449x; 1.0043x over previous
//
#include <hip/hip_runtime.h>
#include <cstdint>
#include <cstddef>

#define GEPS 1e-6f

using bf16x8 = __attribute__((ext_vector_type(8))) short;   // 8 bf16 = 4 VGPRs
using f32x4  = __attribute__((ext_vector_type(4))) float;   // MFMA C/D frag

__device__ inline ushort f2bf(float x) {
    union { float f; uint32_t u; } v; v.f = x;
    uint32_t r = (v.u + 0x7fffu + ((v.u >> 16) & 1u)) >> 16;  // RNE
    return (ushort)r;
}
__device__ inline float bf2f(ushort b) {
    union { float f; uint32_t u; } v; v.u = ((uint32_t)b) << 16;
    return v.f;
}

// async global->LDS, 16 bytes per lane. LDS dest = wave-uniform base + lane*16.
// Global source address IS per-lane (guide §5) -> shifted-conv addressing works.
__device__ inline void gll16(const void* g, void* l) {
    __builtin_amdgcn_global_load_lds(
        (const __attribute__((address_space(1))) void*)g,
        (__attribute__((address_space(3))) void*)l, 16, 0, 0);
}

// ---------------------------------------------------------------------------
// Kernel 1: merged preprocessing (one launch).
//   blocks 0..255     : x -> zero-padded channel-last bf16 Xcl[b][34][34][256]
//   blocks 256..1023  : conv weights -> bf16, k TAP-MAJOR (k = tap*256+ci)
//   blocks 1024..1087 : wo -> bf16 (+ blk 1024 zeroes the fp32 stats accum)
//   blocks 1088..3135 : bias table -> MFMA-fragment-ordered Bx (bf16, DEDICATED)
// ---------------------------------------------------------------------------
__global__ __launch_bounds__(256) void prep_k(
    const float* __restrict__ x,
    const float* __restrict__ wq, const float* __restrict__ wk,
    const float* __restrict__ wv, const float* __restrict__ wo,
    const float* __restrict__ btab,
    ushort* __restrict__ Xcl, ushort* __restrict__ Wbuf,
    ushort* __restrict__ wo_bf, ushort* __restrict__ Bx,
    float* __restrict__ stats)
{
    __shared__ __align__(16) ushort Xs[3 * 34 * 128];   // 25.5 KB (max use)
    int tid = threadIdx.x;
    int blk = blockIdx.x;

    if (blk < 256) {
        // ---- channel-last padded conversion: block = b*32 + y ----
        int b = blk >> 5, y = blk & 31;
#pragma unroll
        for (int it = 0; it < 8; ++it) {
            int idx = it * 256 + tid;           // 0..2047
            int ci = idx >> 3, pxg = idx & 7;
            float4 v = *(const float4*)&x[((size_t)(b * 256 + ci)) * 1024 + y * 32 + pxg * 4];
            int base = (pxg * 4) * 264 + ci;
            Xs[base + 0 * 264] = f2bf(v.x);
            Xs[base + 1 * 264] = f2bf(v.y);
            Xs[base + 2 * 264] = f2bf(v.z);
            Xs[base + 3 * 264] = f2bf(v.w);
        }
        __syncthreads();
        uint4 z4 = make_uint4(0u, 0u, 0u, 0u);
        ushort* orow = Xcl + ((size_t)(b * 34) + y + 1) * 34 * 256;
#pragma unroll
        for (int it = 0; it < 4; ++it) {
            int idx = it * 256 + tid;           // 0..1023
            int px = idx >> 5, ci8 = idx & 31;
            *(uint4*)&orow[(px + 1) * 256 + ci8 * 8] =
                *(const uint4*)&Xs[px * 264 + ci8 * 8];
        }
        if (tid < 64) {                          // x=0 / x=33 border
            int side = tid >> 5, ci8 = tid & 31;
            *(uint4*)&orow[side * 33 * 256 + ci8 * 8] = z4;
        }
        if (y == 0 || y == 31) {                 // y=0 / y=33 border rows
            ushort* zrow = Xcl + ((size_t)(b * 34) + (y == 0 ? 0 : 33)) * 34 * 256;
#pragma unroll
            for (int it = 0; it < 5; ++it) {
                int idx = it * 256 + tid;
                if (idx < 1088) *(uint4*)&zrow[idx * 8] = z4;
            }
        }
        return;
    }
    if (blk < 1024) {
        // ---- conv weight pack (LDS transpose) ----
        int wrow = blk - 256;               // 0..767
        int proj = wrow >> 8, co = wrow & 255;
        const float* src = ((proj == 0) ? wq : ((proj == 1) ? wk : wv)) + (size_t)co * 2304;
#pragma unroll
        for (int j = 0; j < 9; ++j) {
            int idx = j * 256 + tid;
            Xs[idx] = f2bf(src[idx]);       // coalesced fp32 read
        }
        __syncthreads();
        ushort* dst = Wbuf + (size_t)wrow * 2304;
#pragma unroll
        for (int j = 0; j < 9; ++j)          // k = j*256+tid: tap=j, ci=tid
            dst[j * 256 + tid] = Xs[tid * 9 + j];   // coalesced store
        return;
    }
    if (blk < 1088) {
        // ---- wo pack (+ stats zero-init; prep completes before conv GEMM) ----
        if (blk == 1024 && tid < 192) stats[tid] = 0.f;
        int t = (blk - 1024) * 256 + tid;    // 0..16383, 4 elems each
        float4 v = *(const float4*)&wo[(size_t)t * 4];
        union { uint2 u; ushort s[4]; } o;
        o.s[0] = f2bf(v.x); o.s[1] = f2bf(v.y); o.s[2] = f2bf(v.z); o.s[3] = f2bf(v.w);
        *(uint2*)&wo_bf[(size_t)t * 4] = o.u;
        return;
    }
    // ---- Bx expansion ----
    int g = (blk - 1088) * 4 + (tid >> 6);   // tile id 0..8191
    int l = tid & 63;
    int h = g >> 10, qt = (g >> 4) & 63, kt = g & 15;
    int quad = l >> 4, c = l & 15;
    union { uint4 v[2]; ushort s[16]; } o;
#pragma unroll
    for (int f = 0; f < 4; ++f)
#pragma unroll
        for (int r = 0; r < 4; ++r) {
            int qrow = qt * 16 + quad * 4 + r;
            int key = kt * 64 + f * 16 + c;
            int dy = (qrow >> 5) - (key >> 5) + 31;
            int dx = (qrow & 31) - (key & 31) + 31;
            o.s[f * 4 + r] = f2bf(btab[(dy * 63 + dx) * 8 + h]);
        }
    uint4* dst = (uint4*)(Bx + ((size_t)g * 64 + l) * 16);
    dst[0] = o.v[0];
    dst[1] = o.v[1];
}

// ---------------------------------------------------------------------------
// Kernel 2/5: bf16 GEMM  C[M,N] = A[M,K] * B[N,K]^T, 128x64 tile, BK=64,
//   FULL K per block, 2-PHASE DOUBLE-BUFFERED pipeline (T3 minimal recipe):
//   issue next-tile global_load_lds BEFORE computing current tile; one raw
//   s_barrier + explicit vmcnt(0) per K-step AFTER compute, so load latency
//   hides under the 16 MFMAs (vs __syncthreads' pre-compute vmcnt(0) drain,
//   which measured 22% MfmaUtil / 51 us on this kernel).
//   mode 0 (conv as 9 shifted GEMMs): A = Xcl[b][34][34][256], row m=(b,py,px),
//     k=tap*256+ci -> Xcl[b][py+kh][px+kw][ci]. Store bf16 P; fused GroupNorm
//     stats (fp32 block-reduce -> 2 atomicAdds; each block is (proj,b)-pure).
//   mode 1 (out-proj): standard row-major A; store fp32 out[b][o][px] + bias.
// ---------------------------------------------------------------------------
__global__ __launch_bounds__(256, 3) void gemm_bt(
    const ushort* __restrict__ A, const ushort* __restrict__ B,
    int M, int N, int K,
    ushort* __restrict__ Cpart, float* __restrict__ stats,
    float* __restrict__ Cout, const float* __restrict__ bias, int mode)
{
    __shared__ __align__(16) ushort As[2][128 * 64];   // 32 KB
    __shared__ __align__(16) ushort Bs[2][64 * 64];    // 16 KB
    __shared__ float red[8];
    int tid = threadIdx.x;
    int mbase = blockIdx.x * 128, nbase = blockIdx.y * 64;
    int wave = tid >> 6, lane = tid & 63;
    int wm = wave & 1, wn = wave >> 1;          // wave grid 2(M) x 2(N)
    int quad = lane >> 4, c = lane & 15;

    int row_s = tid >> 3;               // 0..31 staging row within chunk
    int cc8 = (tid & 7) ^ (row_s & 7);  // swizzled global column-block

    // conv mode: per-thread shifted-GEMM row bases into Xcl (tap-independent)
    int rb[4];
    if (mode == 0) {
#pragma unroll
        for (int R = 0; R < 4; ++R) {
            int r = mbase + R * 32 + row_s;
            int b_ = r >> 10, yy = (r >> 5) & 31, xx = r & 31;
            rb[R] = ((b_ * 34 + yy) * 34 + xx) * 256;
        }
    }

    // stage one 64-wide K-slab into buffer `buf` (6 x global_load_lds / thread)
    auto stage = [&](int buf, int kb) {
        ushort* ldsA = As[buf] + wave * 512;    // wave-uniform dest (+lane*16B)
        ushort* ldsB = Bs[buf] + wave * 512;
        if (mode == 0) {
            int tap = kb >> 8;                   // uniform (SALU)
            int kh = (tap * 11) >> 5;            // tap/3 for tap in 0..8
            int kw = tap - kh * 3;
            int toff = (kh * 34 + kw) * 256 + (kb & 255) + cc8 * 8;
#pragma unroll
            for (int R = 0; R < 4; ++R)
                gll16(A + rb[R] + toff, ldsA + R * 2048);
#pragma unroll
            for (int S = 0; S < 2; ++S)
                gll16(B + (size_t)(nbase + S * 32 + row_s) * K + kb + cc8 * 8,
                      ldsB + S * 2048);
        } else {
#pragma unroll
            for (int R = 0; R < 4; ++R)
                gll16(A + (size_t)(mbase + R * 32 + row_s) * K + kb + cc8 * 8,
                      ldsA + R * 2048);
#pragma unroll
            for (int S = 0; S < 2; ++S)
                gll16(B + (size_t)(nbase + S * 32 + row_s) * K + kb + cc8 * 8,
                      ldsB + S * 2048);
        }
    };

    f32x4 acc[4][2];
#pragma unroll
    for (int i = 0; i < 4; ++i)
#pragma unroll
        for (int j = 0; j < 2; ++j) acc[i][j] = (f32x4){0.f, 0.f, 0.f, 0.f};

    int nt = K >> 6;
    // prologue: fill buffer 0
    stage(0, 0);
    asm volatile("s_waitcnt vmcnt(0)" ::: "memory");
    __builtin_amdgcn_s_barrier();

    int cur = 0;
    for (int t = 0; t < nt; ++t) {
        if (t + 1 < nt) stage(cur ^ 1, (t + 1) << 6);   // prefetch next slab
#pragma unroll
        for (int kq = 0; kq < 2; ++kq) {
            bf16x8 af[4], bfr[2];
            int sw = ((kq * 4 + quad) ^ (c & 7)) * 8;
#pragma unroll
            for (int i = 0; i < 4; ++i)
                af[i]  = *(const bf16x8*)&As[cur][(wm * 64 + i * 16 + c) * 64 + sw];
#pragma unroll
            for (int j = 0; j < 2; ++j)
                bfr[j] = *(const bf16x8*)&Bs[cur][(wn * 32 + j * 16 + c) * 64 + sw];
#pragma unroll
            for (int i = 0; i < 4; ++i)
#pragma unroll
                for (int j = 0; j < 2; ++j)
                    acc[i][j] = __builtin_amdgcn_mfma_f32_16x16x32_bf16(
                        af[i], bfr[j], acc[i][j], 0, 0, 0);
        }
        if (t + 1 < nt) {
            // prefetch (issued before compute) has had the whole compute phase
            // to land; drain + raw barrier, then swap buffers.
            asm volatile("s_waitcnt vmcnt(0)" ::: "memory");
            __builtin_amdgcn_s_barrier();
            cur ^= 1;
        }
    }

    if (mode == 0) {
        float s1 = 0.f, s2 = 0.f;
#pragma unroll
        for (int i = 0; i < 4; ++i) {
            int mrow = mbase + wm * 64 + i * 16 + quad * 4;
#pragma unroll
            for (int j = 0; j < 2; ++j) {
                int ncol = nbase + wn * 32 + j * 16 + c;
#pragma unroll
                for (int r = 0; r < 4; ++r) {
                    float v = acc[i][j][r];
                    s1 += v; s2 += v * v;
                    Cpart[(size_t)(mrow + r) * N + ncol] = f2bf(v);
                }
            }
        }
#pragma unroll
        for (int mk = 1; mk < 64; mk <<= 1) {
            s1 += __shfl_xor(s1, mk, 64);
            s2 += __shfl_xor(s2, mk, 64);
        }
        if (lane == 0) { red[wave] = s1; red[4 + wave] = s2; }
        __syncthreads();
        if (tid == 0) {
            int key = (blockIdx.y >> 2) * 8 + (blockIdx.x >> 3);   // proj*8 + b
            atomicAdd(&stats[key * 2 + 0], red[0] + red[1] + red[2] + red[3]);
            atomicAdd(&stats[key * 2 + 1], red[4] + red[5] + red[6] + red[7]);
        }
    } else {
#pragma unroll
        for (int i = 0; i < 4; ++i) {
            int mrow0 = mbase + wm * 64 + i * 16 + quad * 4;
#pragma unroll
            for (int j = 0; j < 2; ++j) {
                int ncol = nbase + wn * 32 + j * 16 + c;
                int bb = ncol >> 10, px = ncol & 1023;
#pragma unroll
                for (int r = 0; r < 4; ++r) {
                    int o = mrow0 + r;
                    Cout[((size_t)bb * 256 + o) * 1024 + px] = acc[i][j][r] + bias[o];
                }
            }
        }
    }
}

// ---------------------------------------------------------------------------
// Kernel 3: GroupNorm(1) + exact GELU + head reshape from single bf16 P.
//   q/k -> [b][h][n][d]; V -> fragment order Vx.
// ---------------------------------------------------------------------------
__global__ void gn_k(const ushort* __restrict__ P0,
                     const float* __restrict__ stats,
                     const float* __restrict__ gq, const float* __restrict__ bq,
                     const float* __restrict__ gk, const float* __restrict__ bk,
                     const float* __restrict__ gv, const float* __restrict__ bv,
                     ushort* __restrict__ qb, ushort* __restrict__ kb2,
                     ushort* __restrict__ vx)
{
    int t = blockIdx.x * 256 + threadIdx.x;     // 786432 threads x 8 elems
    int m = t / 96;
    int nn = (t - m * 96) * 8;
    int proj = nn >> 8, co = nn & 255;
    int b = m >> 10, px = m & 1023;
    float s1 = stats[(proj * 8 + b) * 2 + 0];
    float s2 = stats[(proj * 8 + b) * 2 + 1];
    const float Ninv = 1.f / 262144.f;
    float mu = s1 * Ninv;
    float var = fmaxf(s2 * Ninv - mu * mu, 0.f);
    float rsig = rsqrtf(var + GEPS);
    const float* gam = (proj == 0) ? gq : ((proj == 1) ? gk : gv);
    const float* bet = (proj == 0) ? bq : ((proj == 1) ? bk : bv);

    size_t base = (size_t)m * 768 + nn;
    union { uint4 v; ushort s[8]; } a;
    a.v = *(const uint4*)&P0[base];
    union { uint4 v; ushort s[8]; } outp;
#pragma unroll
    for (int e = 0; e < 8; ++e) {
        int cc = co + e;
        float xv = bf2f(a.s[e]);
        float xn = (xv - mu) * rsig * gam[cc] + bet[cc];
        float ge = 0.5f * xn * (1.f + erff(xn * 0.70710678118654752f));
        outp.s[e] = f2bf(ge);
    }
    int h = co >> 5, d = co & 31;
    if (proj == 0) {
        *(uint4*)(qb + ((((size_t)b * 8 + h) * 1024 + px) * 32 + d)) = outp.v;
    } else if (proj == 1) {
        *(uint4*)(kb2 + ((((size_t)b * 8 + h) * 1024 + px) * 32 + d)) = outp.v;
    } else {
        // Vx[bh][kca=px>>5][half=d>>4][lane=quad*16+(d&15)][j=px&7]
        ushort* vb = vx + ((size_t)b * 8 + h) * 32768;
        int kca = px >> 5, quad = (px >> 3) & 3, j = px & 7;
#pragma unroll
        for (int e = 0; e < 8; ++e) {
            int dd = d + e;
            vb[(((kca * 2 + (dd >> 4)) * 64) + quad * 16 + (dd & 15)) * 8 + j] = outp.s[e];
        }
    }
}

// ---------------------------------------------------------------------------
// Kernel 4: fused attention, KEY-SPLIT z=2 (2048 blocks -> 8 blocks/CU, 100%
//   occupancy ceiling — latency-bound kernel needs the TLP; z=1 measured 38%
//   occupancy / 49 µs vs ~27 µs here). Writes UNNORMALIZED bf16 O partials +
//   fp32 l partials; combine_k finishes.
// ---------------------------------------------------------------------------
__global__ __launch_bounds__(256, 8) void attn_k(
    const ushort* __restrict__ qb, const ushort* __restrict__ kb,
    const ushort* __restrict__ vx, const ushort* __restrict__ Bx,
    ushort* __restrict__ Opart, float* __restrict__ lpart)
{
    __shared__ __align__(16) ushort Pl[4 * 16 * 72];
    int tid = threadIdx.x, wave = tid >> 6, lane = tid & 63;
    int quad = lane >> 4, c = lane & 15;
    int bh = blockIdx.y;               // b*8 + h
    int h = bh & 7;
    int z = blockIdx.z;
    int qbase = blockIdx.x * 64 + wave * 16;

    const ushort* Q  = qb + (size_t)bh * 1024 * 32;
    const ushort* Kp = kb + (size_t)bh * 1024 * 32;
    const ushort* Vb = vx + (size_t)bh * 32768;
    const ushort* bxp = Bx + (((size_t)(h * 64 + (qbase >> 4)) * 16) * 64 + lane) * 16;
    ushort* Pw = Pl + wave * 16 * 72;

    bf16x8 qf = *(const bf16x8*)&Q[(qbase + c) * 32 + quad * 8];

    float l_[4] = {0.f, 0.f, 0.f, 0.f};
    f32x4 Of0 = {0.f, 0.f, 0.f, 0.f}, Of1 = {0.f, 0.f, 0.f, 0.f};

    for (int kb64 = z * 512; kb64 < z * 512 + 512; kb64 += 64) {
        f32x4 S[4];
        f32x4 zf = {0.f, 0.f, 0.f, 0.f};
#pragma unroll
        for (int f = 0; f < 4; ++f) {
            bf16x8 kf = *(const bf16x8*)&Kp[(kb64 + f * 16 + c) * 32 + quad * 8];
            S[f] = __builtin_amdgcn_mfma_f32_16x16x32_bf16(qf, kf, zf, 0, 0, 0);
        }
        // fragment-ordered bias: 32 B per lane, coalesced
        union { uint4 v[2]; ushort s[16]; } bu;
        const uint4* bsrc = (const uint4*)(bxp + (size_t)(kb64 >> 6) * 1024);
        bu.v[0] = bsrc[0];
        bu.v[1] = bsrc[1];
#pragma unroll
        for (int f = 0; f < 4; ++f)
#pragma unroll
            for (int r = 0; r < 4; ++r) {
                float p = __expf(S[f][r] + bf2f(bu.s[f * 4 + r]));
                S[f][r] = p;
                l_[r] += p;
            }
        // P (C-layout) -> LDS -> A-layout; per-wave slice, no barrier needed
#pragma unroll
        for (int f = 0; f < 4; ++f)
#pragma unroll
            for (int r = 0; r < 4; ++r)
                Pw[(quad * 4 + r) * 72 + f * 16 + c] = f2bf(S[f][r]);
#pragma unroll
        for (int kc = 0; kc < 2; ++kc) {
            int kca = (kb64 >> 5) + kc;
            bf16x8 pf = *(const bf16x8*)&Pw[c * 72 + kc * 32 + quad * 8];
            bf16x8 vf0 = *(const bf16x8*)&Vb[((kca * 2 + 0) * 64 + lane) * 8];
            Of0 = __builtin_amdgcn_mfma_f32_16x16x32_bf16(pf, vf0, Of0, 0, 0, 0);
            bf16x8 vf1 = *(const bf16x8*)&Vb[((kca * 2 + 1) * 64 + lane) * 8];
            Of1 = __builtin_amdgcn_mfma_f32_16x16x32_bf16(pf, vf1, Of1, 0, 0, 0);
        }
    }
#pragma unroll
    for (int r = 0; r < 4; ++r) {
        float l = l_[r];
        l += __shfl_xor(l, 1, 64);
        l += __shfl_xor(l, 2, 64);
        l += __shfl_xor(l, 4, 64);
        l += __shfl_xor(l, 8, 64);
        int qr = qbase + quad * 4 + r;
        size_t ob = (((size_t)z * 64 + bh) * 1024 + qr) * 32;
        Opart[ob + c]      = f2bf(Of0[r]);
        Opart[ob + 16 + c] = f2bf(Of1[r]);
        if (c == 0) lpart[(size_t)z * 65536 + bh * 1024 + qr] = l;
    }
}

// ---------------------------------------------------------------------------
// Kernel 5: combine key-split partials: attnout = (O0+O1)/(l0+l1), bf16,
//   written in [b][n][h*32+d] layout for the out-proj GEMM.
// ---------------------------------------------------------------------------
__global__ __launch_bounds__(256) void combine_k(const ushort* __restrict__ Opart,
                                                 const float* __restrict__ lpart,
                                                 ushort* __restrict__ attnout)
{
    int t = blockIdx.x * 256 + threadIdx.x;   // 262144 threads, 8 d each
    int g = t & 3;
    int qg = t >> 2;                          // bh*1024 + qr
    int bh = qg >> 10, qr = qg & 1023;
    int b = bh >> 3, h = bh & 7;
    size_t ob = ((size_t)qg) * 32 + g * 8;
    union { uint4 v; ushort s[8]; } o0, o1;
    o0.v = *(const uint4*)&Opart[ob];
    o1.v = *(const uint4*)&Opart[(size_t)64 * 1024 * 32 + ob];
    float inv = 1.f / (lpart[qg] + lpart[65536 + qg]);
    union { uint4 u; ushort s[8]; } o;
#pragma unroll
    for (int e = 0; e < 8; ++e)
        o.s[e] = f2bf((bf2f(o0.s[e]) + bf2f(o1.s[e])) * inv);
    *(uint4*)&attnout[(((size_t)b * 1024 + qr) * 256) + h * 32 + g * 8] = o.u;
}

// ---------------------------------------------------------------------------
extern "C" void kernel_launch(void* const* d_in, const int* in_sizes, int n_in,
                              void* d_out, int out_size, void* d_ws, size_t ws_size,
                              hipStream_t stream)
{
    const float* x    = (const float*)d_in[0];
    const float* wq   = (const float*)d_in[1];
    const float* wk   = (const float*)d_in[2];
    const float* wv   = (const float*)d_in[3];
    const float* gq   = (const float*)d_in[4];
    const float* bq   = (const float*)d_in[5];
    const float* gk   = (const float*)d_in[6];
    const float* bk   = (const float*)d_in[7];
    const float* gv   = (const float*)d_in[8];
    const float* bv   = (const float*)d_in[9];
    const float* btab = (const float*)d_in[10];
    const float* wo   = (const float*)d_in[11];
    const float* bo   = (const float*)d_in[12];
    float* out = (float*)d_out;

    char* w = (char*)d_ws;
    size_t off = 0;
    auto alloc = [&](size_t bytes) -> char* {
        char* p = w + off;
        off += (bytes + 255) & ~(size_t)255;
        return p;
    };
    ushort* Xcl     = (ushort*)alloc(8ull * 34 * 34 * 256 * 2); // padded chan-last x (4.7 MB)
    ushort* Wbuf    = (ushort*)alloc(768ull * 2304 * 2);    // concat conv weights
    ushort* wo_bf   = (ushort*)alloc(65536ull * 2);         // out-proj weight
    ushort* Bx      = (ushort*)alloc(8192ull * 64 * 16 * 2);// bias frags (16.7 MB, DEDICATED)
    ushort* P0      = (ushort*)alloc(8192ull * 768 * 2);    // conv output bf16 (12.6 MB)
    float*  stats   = (float*)alloc(768);                   // [proj][b][sum,sumsq] fp32 accum
    ushort* Opart   = (ushort*)alloc(2ull * 64 * 1024 * 32 * 2);  // attn O partials (bf16)
    float*  lpart   = (float*)alloc(2ull * 64 * 1024 * 4);        // attn l partials
    ushort* qb      = (ushort*)alloc(8ull * 8 * 1024 * 32 * 2);   // 4 MB
    ushort* kb2     = (ushort*)alloc(8ull * 8 * 1024 * 32 * 2);   // 4 MB
    ushort* vx      = (ushort*)alloc(8ull * 8 * 32 * 1024 * 2);   // 4 MB (fragment order)
    ushort* attnout = (ushort*)alloc(8ull * 1024 * 256 * 2);      // 4 MB

    prep_k<<<3136, 256, 0, stream>>>(x, wq, wk, wv, wo, btab,
                                     Xcl, Wbuf, wo_bf, Bx, stats);
    gemm_bt<<<dim3(64, 12, 1), 256, 0, stream>>>(Xcl, Wbuf, 8192, 768, 2304,
                                                 P0, stats, nullptr, nullptr, 0);
    gn_k<<<3072, 256, 0, stream>>>(P0, stats, gq, bq, gk, bk, gv, bv,
                                   qb, kb2, vx);
    attn_k<<<dim3(16, 64, 2), 256, 0, stream>>>(qb, kb2, vx, Bx, Opart, lpart);
    combine_k<<<1024, 256, 0, stream>>>(Opart, lpart, attnout);
    gemm_bt<<<dim3(2, 128, 1), 256, 0, stream>>>(wo_bf, attnout, 256, 8192, 256,
                                                 nullptr, nullptr, out, bo, 1);
}

// Round 5
// 220.172 us; speedup vs baseline: 1.0453x; 1.0005x over previous
//
#include <hip/hip_runtime.h>
#include <cstdint>
#include <cstddef>

#define GEPS 1e-6f

using bf16x8 = __attribute__((ext_vector_type(8))) short;   // 8 bf16 = 4 VGPRs
using f32x4  = __attribute__((ext_vector_type(4))) float;   // MFMA C/D frag

__device__ inline ushort f2bf(float x) {
    union { float f; uint32_t u; } v; v.f = x;
    uint32_t r = (v.u + 0x7fffu + ((v.u >> 16) & 1u)) >> 16;  // RNE
    return (ushort)r;
}
__device__ inline float bf2f(ushort b) {
    union { float f; uint32_t u; } v; v.u = ((uint32_t)b) << 16;
    return v.f;
}

// async global->LDS, 16 bytes per lane. LDS dest = wave-uniform base + lane*16.
// Global source address IS per-lane (guide §5) -> shifted-conv addressing works.
__device__ inline void gll16(const void* g, void* l) {
    __builtin_amdgcn_global_load_lds(
        (const __attribute__((address_space(1))) void*)g,
        (__attribute__((address_space(3))) void*)l, 16, 0, 0);
}

// ---------------------------------------------------------------------------
// Kernel 1: merged preprocessing (one launch).
//   blocks 0..255     : x -> zero-padded channel-last bf16 Xcl[b][34][34][256]
//   blocks 256..1023  : conv weights -> bf16, k TAP-MAJOR (k = tap*256+ci)
//   blocks 1024..1087 : wo -> bf16 (+ blk 1024 zeroes the fp32 stats accum)
//   blocks 1088..3135 : bias table -> MFMA-fragment-ordered Bx (bf16, DEDICATED)
// ---------------------------------------------------------------------------
__global__ __launch_bounds__(256) void prep_k(
    const float* __restrict__ x,
    const float* __restrict__ wq, const float* __restrict__ wk,
    const float* __restrict__ wv, const float* __restrict__ wo,
    const float* __restrict__ btab,
    ushort* __restrict__ Xcl, ushort* __restrict__ Wbuf,
    ushort* __restrict__ wo_bf, ushort* __restrict__ Bx,
    float* __restrict__ stats)
{
    __shared__ __align__(16) ushort Xs[3 * 34 * 128];   // 25.5 KB (max use)
    int tid = threadIdx.x;
    int blk = blockIdx.x;

    if (blk < 256) {
        // ---- channel-last padded conversion: block = b*32 + y ----
        int b = blk >> 5, y = blk & 31;
#pragma unroll
        for (int it = 0; it < 8; ++it) {
            int idx = it * 256 + tid;           // 0..2047
            int ci = idx >> 3, pxg = idx & 7;
            float4 v = *(const float4*)&x[((size_t)(b * 256 + ci)) * 1024 + y * 32 + pxg * 4];
            int base = (pxg * 4) * 264 + ci;
            Xs[base + 0 * 264] = f2bf(v.x);
            Xs[base + 1 * 264] = f2bf(v.y);
            Xs[base + 2 * 264] = f2bf(v.z);
            Xs[base + 3 * 264] = f2bf(v.w);
        }
        __syncthreads();
        uint4 z4 = make_uint4(0u, 0u, 0u, 0u);
        ushort* orow = Xcl + ((size_t)(b * 34) + y + 1) * 34 * 256;
#pragma unroll
        for (int it = 0; it < 4; ++it) {
            int idx = it * 256 + tid;           // 0..1023
            int px = idx >> 5, ci8 = idx & 31;
            *(uint4*)&orow[(px + 1) * 256 + ci8 * 8] =
                *(const uint4*)&Xs[px * 264 + ci8 * 8];
        }
        if (tid < 64) {                          // x=0 / x=33 border
            int side = tid >> 5, ci8 = tid & 31;
            *(uint4*)&orow[side * 33 * 256 + ci8 * 8] = z4;
        }
        if (y == 0 || y == 31) {                 // y=0 / y=33 border rows
            ushort* zrow = Xcl + ((size_t)(b * 34) + (y == 0 ? 0 : 33)) * 34 * 256;
#pragma unroll
            for (int it = 0; it < 5; ++it) {
                int idx = it * 256 + tid;
                if (idx < 1088) *(uint4*)&zrow[idx * 8] = z4;
            }
        }
        return;
    }
    if (blk < 1024) {
        // ---- conv weight pack (LDS transpose) ----
        int wrow = blk - 256;               // 0..767
        int proj = wrow >> 8, co = wrow & 255;
        const float* src = ((proj == 0) ? wq : ((proj == 1) ? wk : wv)) + (size_t)co * 2304;
#pragma unroll
        for (int j = 0; j < 9; ++j) {
            int idx = j * 256 + tid;
            Xs[idx] = f2bf(src[idx]);       // coalesced fp32 read
        }
        __syncthreads();
        ushort* dst = Wbuf + (size_t)wrow * 2304;
#pragma unroll
        for (int j = 0; j < 9; ++j)          // k = j*256+tid: tap=j, ci=tid
            dst[j * 256 + tid] = Xs[tid * 9 + j];   // coalesced store
        return;
    }
    if (blk < 1088) {
        // ---- wo pack (+ stats zero-init; prep completes before conv GEMM) ----
        if (blk == 1024 && tid < 192) stats[tid] = 0.f;
        int t = (blk - 1024) * 256 + tid;    // 0..16383, 4 elems each
        float4 v = *(const float4*)&wo[(size_t)t * 4];
        union { uint2 u; ushort s[4]; } o;
        o.s[0] = f2bf(v.x); o.s[1] = f2bf(v.y); o.s[2] = f2bf(v.z); o.s[3] = f2bf(v.w);
        *(uint2*)&wo_bf[(size_t)t * 4] = o.u;
        return;
    }
    // ---- Bx expansion ----
    int g = (blk - 1088) * 4 + (tid >> 6);   // tile id 0..8191
    int l = tid & 63;
    int h = g >> 10, qt = (g >> 4) & 63, kt = g & 15;
    int quad = l >> 4, c = l & 15;
    union { uint4 v[2]; ushort s[16]; } o;
#pragma unroll
    for (int f = 0; f < 4; ++f)
#pragma unroll
        for (int r = 0; r < 4; ++r) {
            int qrow = qt * 16 + quad * 4 + r;
            int key = kt * 64 + f * 16 + c;
            int dy = (qrow >> 5) - (key >> 5) + 31;
            int dx = (qrow & 31) - (key & 31) + 31;
            o.s[f * 4 + r] = f2bf(btab[(dy * 63 + dx) * 8 + h]);
        }
    uint4* dst = (uint4*)(Bx + ((size_t)g * 64 + l) * 16);
    dst[0] = o.v[0];
    dst[1] = o.v[1];
}

// ---------------------------------------------------------------------------
// Kernel 2/5: bf16 GEMM  C[M,N] = A[M,K] * B[N,K]^T, 128x64 tile, BK=64,
//   FULL K per block, 2-phase double-buffered pipeline.
//   mode 0: XCD-CHUNKED BLOCK SWIZZLE (T1): flat%8 = XCD (HW round-robin);
//     XCD c owns mtiles [c*8,c*8+8) (= batch image b=c, Xcl slice 578 KB) x
//     all 12 ntiles (full Wbuf 3.4 MB) -> per-XCD L2 working set ~3.95 MB
//     < 4 MiB, converting the L3-streamed staging (measured 13.3 TB/s agg,
//     MfmaUtil 22%) into L2 hits. ntile varies fastest -> A-panel reused 12x.
//   mode 0 epilogue: fused GroupNorm stats (fp32 block-reduce -> 2 atomicAdds;
//     each block is (proj,b)-pure). mode 1 (out-proj): fp32 out + bias.
// ---------------------------------------------------------------------------
__global__ __launch_bounds__(256, 3) void gemm_bt(
    const ushort* __restrict__ A, const ushort* __restrict__ B,
    int M, int N, int K,
    ushort* __restrict__ Cpart, float* __restrict__ stats,
    float* __restrict__ Cout, const float* __restrict__ bias, int mode)
{
    __shared__ __align__(16) ushort As[2][128 * 64];   // 32 KB
    __shared__ __align__(16) ushort Bs[2][64 * 64];    // 16 KB
    __shared__ float red[8];
    int tid = threadIdx.x;

    // block index remap (mode 0 only): see header comment
    int mtile, ntile;
    if (mode == 0) {
        int flat = blockIdx.y * gridDim.x + blockIdx.x;  // 0..767
        int chunk = flat & 7;                // XCD id under round-robin dispatch
        int within = flat >> 3;              // 0..95 on this XCD
        mtile = chunk * 8 + within / 12;     // 8 mtiles per XCD (= one image)
        ntile = within % 12;                 // fastest-varying -> A reuse
    } else {
        mtile = blockIdx.x;
        ntile = blockIdx.y;
    }
    int mbase = mtile * 128, nbase = ntile * 64;

    int wave = tid >> 6, lane = tid & 63;
    int wm = wave & 1, wn = wave >> 1;          // wave grid 2(M) x 2(N)
    int quad = lane >> 4, c = lane & 15;

    int row_s = tid >> 3;               // 0..31 staging row within chunk
    int cc8 = (tid & 7) ^ (row_s & 7);  // swizzled global column-block

    // conv mode: per-thread shifted-GEMM row bases into Xcl (tap-independent)
    int rb[4];
    if (mode == 0) {
#pragma unroll
        for (int R = 0; R < 4; ++R) {
            int r = mbase + R * 32 + row_s;
            int b_ = r >> 10, yy = (r >> 5) & 31, xx = r & 31;
            rb[R] = ((b_ * 34 + yy) * 34 + xx) * 256;
        }
    }

    // stage one 64-wide K-slab into buffer `buf` (6 x global_load_lds / thread)
    auto stage = [&](int buf, int kb) {
        ushort* ldsA = As[buf] + wave * 512;    // wave-uniform dest (+lane*16B)
        ushort* ldsB = Bs[buf] + wave * 512;
        if (mode == 0) {
            int tap = kb >> 8;                   // uniform (SALU)
            int kh = (tap * 11) >> 5;            // tap/3 for tap in 0..8
            int kw = tap - kh * 3;
            int toff = (kh * 34 + kw) * 256 + (kb & 255) + cc8 * 8;
#pragma unroll
            for (int R = 0; R < 4; ++R)
                gll16(A + rb[R] + toff, ldsA + R * 2048);
#pragma unroll
            for (int S = 0; S < 2; ++S)
                gll16(B + (size_t)(nbase + S * 32 + row_s) * K + kb + cc8 * 8,
                      ldsB + S * 2048);
        } else {
#pragma unroll
            for (int R = 0; R < 4; ++R)
                gll16(A + (size_t)(mbase + R * 32 + row_s) * K + kb + cc8 * 8,
                      ldsA + R * 2048);
#pragma unroll
            for (int S = 0; S < 2; ++S)
                gll16(B + (size_t)(nbase + S * 32 + row_s) * K + kb + cc8 * 8,
                      ldsB + S * 2048);
        }
    };

    f32x4 acc[4][2];
#pragma unroll
    for (int i = 0; i < 4; ++i)
#pragma unroll
        for (int j = 0; j < 2; ++j) acc[i][j] = (f32x4){0.f, 0.f, 0.f, 0.f};

    int nt = K >> 6;
    // prologue: fill buffer 0
    stage(0, 0);
    asm volatile("s_waitcnt vmcnt(0)" ::: "memory");
    __builtin_amdgcn_s_barrier();

    int cur = 0;
    for (int t = 0; t < nt; ++t) {
        if (t + 1 < nt) stage(cur ^ 1, (t + 1) << 6);   // prefetch next slab
#pragma unroll
        for (int kq = 0; kq < 2; ++kq) {
            bf16x8 af[4], bfr[2];
            int sw = ((kq * 4 + quad) ^ (c & 7)) * 8;
#pragma unroll
            for (int i = 0; i < 4; ++i)
                af[i]  = *(const bf16x8*)&As[cur][(wm * 64 + i * 16 + c) * 64 + sw];
#pragma unroll
            for (int j = 0; j < 2; ++j)
                bfr[j] = *(const bf16x8*)&Bs[cur][(wn * 32 + j * 16 + c) * 64 + sw];
#pragma unroll
            for (int i = 0; i < 4; ++i)
#pragma unroll
                for (int j = 0; j < 2; ++j)
                    acc[i][j] = __builtin_amdgcn_mfma_f32_16x16x32_bf16(
                        af[i], bfr[j], acc[i][j], 0, 0, 0);
        }
        if (t + 1 < nt) {
            // prefetch (issued before compute) has had the whole compute phase
            // to land; drain + raw barrier, then swap buffers.
            asm volatile("s_waitcnt vmcnt(0)" ::: "memory");
            __builtin_amdgcn_s_barrier();
            cur ^= 1;
        }
    }

    if (mode == 0) {
        float s1 = 0.f, s2 = 0.f;
#pragma unroll
        for (int i = 0; i < 4; ++i) {
            int mrow = mbase + wm * 64 + i * 16 + quad * 4;
#pragma unroll
            for (int j = 0; j < 2; ++j) {
                int ncol = nbase + wn * 32 + j * 16 + c;
#pragma unroll
                for (int r = 0; r < 4; ++r) {
                    float v = acc[i][j][r];
                    s1 += v; s2 += v * v;
                    Cpart[(size_t)(mrow + r) * N + ncol] = f2bf(v);
                }
            }
        }
#pragma unroll
        for (int mk = 1; mk < 64; mk <<= 1) {
            s1 += __shfl_xor(s1, mk, 64);
            s2 += __shfl_xor(s2, mk, 64);
        }
        if (lane == 0) { red[wave] = s1; red[4 + wave] = s2; }
        __syncthreads();
        if (tid == 0) {
            int key = (ntile >> 2) * 8 + (mtile >> 3);   // proj*8 + b
            atomicAdd(&stats[key * 2 + 0], red[0] + red[1] + red[2] + red[3]);
            atomicAdd(&stats[key * 2 + 1], red[4] + red[5] + red[6] + red[7]);
        }
    } else {
#pragma unroll
        for (int i = 0; i < 4; ++i) {
            int mrow0 = mbase + wm * 64 + i * 16 + quad * 4;
#pragma unroll
            for (int j = 0; j < 2; ++j) {
                int ncol = nbase + wn * 32 + j * 16 + c;
                int bb = ncol >> 10, px = ncol & 1023;
#pragma unroll
                for (int r = 0; r < 4; ++r) {
                    int o = mrow0 + r;
                    Cout[((size_t)bb * 256 + o) * 1024 + px] = acc[i][j][r] + bias[o];
                }
            }
        }
    }
}

// ---------------------------------------------------------------------------
// Kernel 3: GroupNorm(1) + exact GELU + head reshape from single bf16 P.
//   q/k -> [b][h][n][d]; V -> fragment order Vx.
// ---------------------------------------------------------------------------
__global__ void gn_k(const ushort* __restrict__ P0,
                     const float* __restrict__ stats,
                     const float* __restrict__ gq, const float* __restrict__ bq,
                     const float* __restrict__ gk, const float* __restrict__ bk,
                     const float* __restrict__ gv, const float* __restrict__ bv,
                     ushort* __restrict__ qb, ushort* __restrict__ kb2,
                     ushort* __restrict__ vx)
{
    int t = blockIdx.x * 256 + threadIdx.x;     // 786432 threads x 8 elems
    int m = t / 96;
    int nn = (t - m * 96) * 8;
    int proj = nn >> 8, co = nn & 255;
    int b = m >> 10, px = m & 1023;
    float s1 = stats[(proj * 8 + b) * 2 + 0];
    float s2 = stats[(proj * 8 + b) * 2 + 1];
    const float Ninv = 1.f / 262144.f;
    float mu = s1 * Ninv;
    float var = fmaxf(s2 * Ninv - mu * mu, 0.f);
    float rsig = rsqrtf(var + GEPS);
    const float* gam = (proj == 0) ? gq : ((proj == 1) ? gk : gv);
    const float* bet = (proj == 0) ? bq : ((proj == 1) ? bk : bv);

    size_t base = (size_t)m * 768 + nn;
    union { uint4 v; ushort s[8]; } a;
    a.v = *(const uint4*)&P0[base];
    union { uint4 v; ushort s[8]; } outp;
#pragma unroll
    for (int e = 0; e < 8; ++e) {
        int cc = co + e;
        float xv = bf2f(a.s[e]);
        float xn = (xv - mu) * rsig * gam[cc] + bet[cc];
        float ge = 0.5f * xn * (1.f + erff(xn * 0.70710678118654752f));
        outp.s[e] = f2bf(ge);
    }
    int h = co >> 5, d = co & 31;
    if (proj == 0) {
        *(uint4*)(qb + ((((size_t)b * 8 + h) * 1024 + px) * 32 + d)) = outp.v;
    } else if (proj == 1) {
        *(uint4*)(kb2 + ((((size_t)b * 8 + h) * 1024 + px) * 32 + d)) = outp.v;
    } else {
        // Vx[bh][kca=px>>5][half=d>>4][lane=quad*16+(d&15)][j=px&7]
        ushort* vb = vx + ((size_t)b * 8 + h) * 32768;
        int kca = px >> 5, quad = (px >> 3) & 3, j = px & 7;
#pragma unroll
        for (int e = 0; e < 8; ++e) {
            int dd = d + e;
            vb[(((kca * 2 + (dd >> 4)) * 64) + quad * 16 + (dd & 15)) * 8 + j] = outp.s[e];
        }
    }
}

// ---------------------------------------------------------------------------
// Kernel 4: fused attention, KEY-SPLIT z=2 (2048 blocks -> 8 blocks/CU, 100%
//   occupancy ceiling — latency-bound kernel needs the TLP; z=1 measured 38%
//   occupancy / 49 µs vs ~27 µs here). Writes UNNORMALIZED bf16 O partials +
//   fp32 l partials; combine_k finishes.
// ---------------------------------------------------------------------------
__global__ __launch_bounds__(256, 8) void attn_k(
    const ushort* __restrict__ qb, const ushort* __restrict__ kb,
    const ushort* __restrict__ vx, const ushort* __restrict__ Bx,
    ushort* __restrict__ Opart, float* __restrict__ lpart)
{
    __shared__ __align__(16) ushort Pl[4 * 16 * 72];
    int tid = threadIdx.x, wave = tid >> 6, lane = tid & 63;
    int quad = lane >> 4, c = lane & 15;
    int bh = blockIdx.y;               // b*8 + h
    int h = bh & 7;
    int z = blockIdx.z;
    int qbase = blockIdx.x * 64 + wave * 16;

    const ushort* Q  = qb + (size_t)bh * 1024 * 32;
    const ushort* Kp = kb + (size_t)bh * 1024 * 32;
    const ushort* Vb = vx + (size_t)bh * 32768;
    const ushort* bxp = Bx + (((size_t)(h * 64 + (qbase >> 4)) * 16) * 64 + lane) * 16;
    ushort* Pw = Pl + wave * 16 * 72;

    bf16x8 qf = *(const bf16x8*)&Q[(qbase + c) * 32 + quad * 8];

    float l_[4] = {0.f, 0.f, 0.f, 0.f};
    f32x4 Of0 = {0.f, 0.f, 0.f, 0.f}, Of1 = {0.f, 0.f, 0.f, 0.f};

    for (int kb64 = z * 512; kb64 < z * 512 + 512; kb64 += 64) {
        f32x4 S[4];
        f32x4 zf = {0.f, 0.f, 0.f, 0.f};
#pragma unroll
        for (int f = 0; f < 4; ++f) {
            bf16x8 kf = *(const bf16x8*)&Kp[(kb64 + f * 16 + c) * 32 + quad * 8];
            S[f] = __builtin_amdgcn_mfma_f32_16x16x32_bf16(qf, kf, zf, 0, 0, 0);
        }
        // fragment-ordered bias: 32 B per lane, coalesced
        union { uint4 v[2]; ushort s[16]; } bu;
        const uint4* bsrc = (const uint4*)(bxp + (size_t)(kb64 >> 6) * 1024);
        bu.v[0] = bsrc[0];
        bu.v[1] = bsrc[1];
#pragma unroll
        for (int f = 0; f < 4; ++f)
#pragma unroll
            for (int r = 0; r < 4; ++r) {
                float p = __expf(S[f][r] + bf2f(bu.s[f * 4 + r]));
                S[f][r] = p;
                l_[r] += p;
            }
        // P (C-layout) -> LDS -> A-layout; per-wave slice, no barrier needed
#pragma unroll
        for (int f = 0; f < 4; ++f)
#pragma unroll
            for (int r = 0; r < 4; ++r)
                Pw[(quad * 4 + r) * 72 + f * 16 + c] = f2bf(S[f][r]);
#pragma unroll
        for (int kc = 0; kc < 2; ++kc) {
            int kca = (kb64 >> 5) + kc;
            bf16x8 pf = *(const bf16x8*)&Pw[c * 72 + kc * 32 + quad * 8];
            bf16x8 vf0 = *(const bf16x8*)&Vb[((kca * 2 + 0) * 64 + lane) * 8];
            Of0 = __builtin_amdgcn_mfma_f32_16x16x32_bf16(pf, vf0, Of0, 0, 0, 0);
            bf16x8 vf1 = *(const bf16x8*)&Vb[((kca * 2 + 1) * 64 + lane) * 8];
            Of1 = __builtin_amdgcn_mfma_f32_16x16x32_bf16(pf, vf1, Of1, 0, 0, 0);
        }
    }
#pragma unroll
    for (int r = 0; r < 4; ++r) {
        float l = l_[r];
        l += __shfl_xor(l, 1, 64);
        l += __shfl_xor(l, 2, 64);
        l += __shfl_xor(l, 4, 64);
        l += __shfl_xor(l, 8, 64);
        int qr = qbase + quad * 4 + r;
        size_t ob = (((size_t)z * 64 + bh) * 1024 + qr) * 32;
        Opart[ob + c]      = f2bf(Of0[r]);
        Opart[ob + 16 + c] = f2bf(Of1[r]);
        if (c == 0) lpart[(size_t)z * 65536 + bh * 1024 + qr] = l;
    }
}

// ---------------------------------------------------------------------------
// Kernel 5: combine key-split partials: attnout = (O0+O1)/(l0+l1), bf16,
//   written in [b][n][h*32+d] layout for the out-proj GEMM.
// ---------------------------------------------------------------------------
__global__ __launch_bounds__(256) void combine_k(const ushort* __restrict__ Opart,
                                                 const float* __restrict__ lpart,
                                                 ushort* __restrict__ attnout)
{
    int t = blockIdx.x * 256 + threadIdx.x;   // 262144 threads, 8 d each
    int g = t & 3;
    int qg = t >> 2;                          // bh*1024 + qr
    int bh = qg >> 10, qr = qg & 1023;
    int b = bh >> 3, h = bh & 7;
    size_t ob = ((size_t)qg) * 32 + g * 8;
    union { uint4 v; ushort s[8]; } o0, o1;
    o0.v = *(const uint4*)&Opart[ob];
    o1.v = *(const uint4*)&Opart[(size_t)64 * 1024 * 32 + ob];
    float inv = 1.f / (lpart[qg] + lpart[65536 + qg]);
    union { uint4 u; ushort s[8]; } o;
#pragma unroll
    for (int e = 0; e < 8; ++e)
        o.s[e] = f2bf((bf2f(o0.s[e]) + bf2f(o1.s[e])) * inv);
    *(uint4*)&attnout[(((size_t)b * 1024 + qr) * 256) + h * 32 + g * 8] = o.u;
}

// ---------------------------------------------------------------------------
extern "C" void kernel_launch(void* const* d_in, const int* in_sizes, int n_in,
                              void* d_out, int out_size, void* d_ws, size_t ws_size,
                              hipStream_t stream)
{
    const float* x    = (const float*)d_in[0];
    const float* wq   = (const float*)d_in[1];
    const float* wk   = (const float*)d_in[2];
    const float* wv   = (const float*)d_in[3];
    const float* gq   = (const float*)d_in[4];
    const float* bq   = (const float*)d_in[5];
    const float* gk   = (const float*)d_in[6];
    const float* bk   = (const float*)d_in[7];
    const float* gv   = (const float*)d_in[8];
    const float* bv   = (const float*)d_in[9];
    const float* btab = (const float*)d_in[10];
    const float* wo   = (const float*)d_in[11];
    const float* bo   = (const float*)d_in[12];
    float* out = (float*)d_out;

    char* w = (char*)d_ws;
    size_t off = 0;
    auto alloc = [&](size_t bytes) -> char* {
        char* p = w + off;
        off += (bytes + 255) & ~(size_t)255;
        return p;
    };
    ushort* Xcl     = (ushort*)alloc(8ull * 34 * 34 * 256 * 2); // padded chan-last x (4.7 MB)
    ushort* Wbuf    = (ushort*)alloc(768ull * 2304 * 2);    // concat conv weights
    ushort* wo_bf   = (ushort*)alloc(65536ull * 2);         // out-proj weight
    ushort* Bx      = (ushort*)alloc(8192ull * 64 * 16 * 2);// bias frags (16.7 MB, DEDICATED)
    ushort* P0      = (ushort*)alloc(8192ull * 768 * 2);    // conv output bf16 (12.6 MB)
    float*  stats   = (float*)alloc(768);                   // [proj][b][sum,sumsq] fp32 accum
    ushort* Opart   = (ushort*)alloc(2ull * 64 * 1024 * 32 * 2);  // attn O partials (bf16)
    float*  lpart   = (float*)alloc(2ull * 64 * 1024 * 4);        // attn l partials
    ushort* qb      = (ushort*)alloc(8ull * 8 * 1024 * 32 * 2);   // 4 MB
    ushort* kb2     = (ushort*)alloc(8ull * 8 * 1024 * 32 * 2);   // 4 MB
    ushort* vx      = (ushort*)alloc(8ull * 8 * 32 * 1024 * 2);   // 4 MB (fragment order)
    ushort* attnout = (ushort*)alloc(8ull * 1024 * 256 * 2);      // 4 MB

    prep_k<<<3136, 256, 0, stream>>>(x, wq, wk, wv, wo, btab,
                                     Xcl, Wbuf, wo_bf, Bx, stats);
    gemm_bt<<<dim3(64, 12, 1), 256, 0, stream>>>(Xcl, Wbuf, 8192, 768, 2304,
                                                 P0, stats, nullptr, nullptr, 0);
    gn_k<<<3072, 256, 0, stream>>>(P0, stats, gq, bq, gk, bk, gv, bv,
                                   qb, kb2, vx);
    attn_k<<<dim3(16, 64, 2), 256, 0, stream>>>(qb, kb2, vx, Bx, Opart, lpart);
    combine_k<<<1024, 256, 0, stream>>>(Opart, lpart, attnout);
    gemm_bt<<<dim3(2, 128, 1), 256, 0, stream>>>(wo_bf, attnout, 256, 8192, 256,
                                                 nullptr, nullptr, out, bo, 1);
}